// Round 8
// baseline (246.615 us; speedup 1.0000x reference)
//
#include <hip/hip_runtime.h>
#include <hip/hip_bf16.h>

// Problem constants
#define NB   8      // batch
#define NM   288    // Bkk = 32*3*3
#define NN   1152   // Cww = 32*6*6
#define NUV  36     // w*w
#define ND   16

// ws layout (float offsets; P/Wt regions hold bf16 in half the space)
#define OFF_P    0
#define SZ_P     (NB*NUV*NM*ND)      // patches, bf16 [b][uv][m][k*4+j]
#define OFF_WT   (OFF_P + SZ_P)
#define SZ_WT    (32*NM*ND)          // W transposed, bf16 [z][m][i*4+j]
#define OFF_ACT  (OFF_WT + SZ_WT)
#define SZ_ACT   (NB*NUV*NM)         // act LINEAR, f32 [b][uv][m]
#define OFF_L    (OFF_ACT + SZ_ACT)
#define SZ_L     (NB*NN*NM)          // A = ap (linear), f32 [b][n][m]
#define OFF_S    (OFF_L + SZ_L)
#define SZ_S     (NB*NM)             // S[b][m] = sum_n A
#define OFF_PS   (OFF_S + SZ_S)
#define SZ_PS    (NB*NUV*NM)         // sum stage-1 partials, [b][c][m]
#define OFF_FLAG (OFF_PS + SZ_PS)    // dtype flag

#define HALF_LOG_2PI 0.9189385332046727f
#define INV_NN       (1.0f/1152.0f)

__device__ __forceinline__ float ldin(const void* p, int i, int f32) {
    return f32 ? ((const float*)p)[i]
               : __bfloat162float(((const __hip_bfloat16*)p)[i]);
}

__device__ __forceinline__ unsigned short bfbits(float f) {
    __hip_bfloat16 h = __float2bfloat16(f);
    return __builtin_bit_cast(unsigned short, h);
}

// packed bf16x2 dot with f32 accumulate: d = a.lo*b.lo + a.hi*b.hi + c
__device__ __forceinline__ float dot2bf(unsigned a, unsigned b, float c) {
    float d;
    asm("v_dot2_f32_bf16 %0, %1, %2, %3" : "=v"(d) : "v"(a), "v"(b), "v"(c));
    return d;
}

// inline dtype sniff (r3-r13 verified: flag==0 on this harness)
__device__ __forceinline__ int sniff(const unsigned short* u16) {
    int wild = 0;
    for (int i = 0; i < 64; ++i) {
        int ex = (u16[i] >> 7) & 0xFF;
        if (ex >= 133) ++wild;
    }
    return (wild >= 4) ? 1 : 0;
}

// (b,s)-tiled prep: stage poses[b,:,s,:,:] + acts[b,s,:,:] in LDS, emit bf16 P
// (uint4 stores) and f32 act (LINEAR). Blocks 256..291 transpose W.
__global__ __launch_bounds__(256) void prep_kernel(
    const void* __restrict__ poses, const void* __restrict__ acts,
    const void* __restrict__ Wb, __hip_bfloat16* __restrict__ P,
    __hip_bfloat16* __restrict__ Wt, float* __restrict__ A36,
    int* __restrict__ flagw)
{
    const int blk = blockIdx.x;
    const int tid = threadIdx.x;
    __shared__ int lflag;
    if (tid == 0) {
        int f = sniff((const unsigned short*)poses);
        lflag = f;
        if (blk == 0) *flagw = f;
    }
    __syncthreads();
    const int f32 = lflag;

    if (blk < 256) {
        __shared__ float ps[16 * 196];
        __shared__ float asld[196];
        const int b = blk >> 5, s = blk & 31;
        for (int e = tid; e < 16 * 196; e += 256) {
            int c = e / 196, hw = e % 196;
            ps[e] = ldin(poses, ((b * 16 + c) * 32 + s) * 196 + hw, f32);
        }
        for (int e = tid; e < 196; e += 256)
            asld[e] = ldin(acts, (b * 32 + s) * 196 + e, f32);
        __syncthreads();
        // P emit: 324 rows x 2 halves; one uint4 (8 bf16) per work item
        for (int o2 = tid; o2 < 648; o2 += 256) {
            int row = o2 >> 1, half = o2 & 1;
            int uv = row / 9, xy = row % 9;
            int u = uv / 6, vv2 = uv % 6;
            int x = xy / 3, y = xy % 3;
            unsigned pk[4];
#pragma unroll
            for (int h = 0; h < 4; ++h) {
                unsigned lohi[2];
#pragma unroll
                for (int e = 0; e < 2; ++e) {
                    int kj = half * 8 + h * 2 + e;
                    int k = kj >> 2, j = kj & 3;
                    int idx = u * 96 + vv2 * 16 + j * 4 + k;   // torch view scramble
                    int c = idx / 36, rem = idx % 36;
                    int wi = rem / 6, wj = rem % 6;
                    lohi[e] = bfbits(ps[c * 196 + (2 * wi + x) * 14 + (2 * wj + y)]);
                }
                pk[h] = lohi[0] | (lohi[1] << 16);
            }
            *((uint4*)(P + (((size_t)((b * 36 + uv) * 288 + s * 9 + xy)) << 4) + half * 8)) =
                make_uint4(pk[0], pk[1], pk[2], pk[3]);
        }
        for (int o = tid; o < 324; o += 256) {
            int uv = o / 9, xy = o % 9;
            int u = uv / 6, vv2 = uv % 6;
            int x = xy / 3, y = xy % 3;
            A36[(b * 36 + uv) * 288 + s * 9 + xy] =
                asld[(2 * u + x) * 14 + (2 * vv2 + y)];    // linear act
        }
    } else {
        int idx = (blk - 256) * 256 + tid;    // 0..9215 (z,m) pairs
        int z = idx / 288, m = idx % 288;
        unsigned pk[8];
#pragma unroll
        for (int h = 0; h < 8; ++h) {
            unsigned lo = bfbits(ldin(Wb, m * 512 + z * 16 + 2 * h, f32));
            unsigned hi = bfbits(ldin(Wb, m * 512 + z * 16 + 2 * h + 1, f32));
            pk[h] = lo | (hi << 16);
        }
        uint4* dst = (uint4*)(Wt + idx * 16);
        dst[0] = make_uint4(pk[0], pk[1], pk[2], pk[3]);
        dst[1] = make_uint4(pk[4], pk[5], pk[6], pk[7]);
    }
}

// TWO n per 288-thread block (z and z+16 of the same g): barrier count per n
// halves, dot2/colsum/exp streams double per-thread ILP (r4 counters: VALU
// issue ~20%, VGPR 28 — huge headroom), and P/act loads are shared. Block
// width stays 4.5 waves (r6 lesson: 9-wave barriers regress). r7 lesson:
// shuffle fold in colsum costs more than it saves — plain 18-chunk partials.
// Linear EM throughout (w = R*act; A = act*sum exp; no log/LSE).
// XCD swizzle: blockIdx = (g>>3)*128 + zp*8 + (g&7), g = b*36+uv, zp in [0,16).
__global__ __launch_bounds__(288, 2) void em_iter(
    const unsigned short* __restrict__ wsP, const unsigned short* __restrict__ wsWt,
    const float* __restrict__ wsA, float* __restrict__ wsL,
    const float* __restrict__ wsS,
    const void* __restrict__ beta_v,
    const void* __restrict__ beta_a,
    const void* __restrict__ lambda_,
    void* __restrict__ outv, const int* __restrict__ flagp, int iter)
{
    __shared__ float red[2 * NM * 17];   // [h][m][col]: 0..15 = v[d], 16 = w (39.2 KB)
    __shared__ float paru[2 * NM];       // [h][d*18+c] partial sum(w*v)
    __shared__ float parv[2 * NM];       // [h][d*18+c] partial sum(w*v*v)
    __shared__ float paruW[2 * 18];      // [h][c] partial sum(w)
    __shared__ float mul[2][16], nhil[2][16], ltl[2][16], ssl[2][16];

    const int tid = threadIdx.x;          // == m
    const int B   = blockIdx.x;
    const int rr  = B & 127;
    const int zp  = rr >> 3;                      // 0..15
    const int g   = ((B >> 7) << 3) | (rr & 7);   // b*36+uv
    const int b   = g / NUV;
    const int uv  = g % NUV;
    const int z0  = zp, z1 = zp + 16;
    const int bn0 = b * NN + z0 * NUV + uv;
    const int bn1 = bn0 + 16 * NUV;               // z1*NUV+uv

    // all global loads issued up front (bf16 W/P rows stay packed)
    const uint4* Wq0 = (const uint4*)(wsWt + ((z0 * NM + tid) << 4));
    const uint4* Wq1 = (const uint4*)(wsWt + ((z1 * NM + tid) << 4));
    const uint4* Pq  = (const uint4*)(wsP + ((g * NM + tid) << 4));
    uint4 wa0 = Wq0[0], wa1 = Wq0[1];
    uint4 wb0 = Wq1[0], wb1 = Wq1[1];
    uint4 pq0 = Pq[0],  pq1 = Pq[1];
    const float act = wsA[g * NM + tid];   // linear act (shared by both n)
    float w0, w1;
    if (iter == 0) {
        w0 = act * INV_NN;
        w1 = w0;
    } else {
        float Sv  = wsS[b * NM + tid];
        float ai  = act / Sv;
        w0 = wsL[(size_t)bn0 * NM + tid] * ai;   // R*act, linear
        w1 = wsL[(size_t)bn1 * NM + tid] * ai;
    }

    // votes: v[i*4+k] = sum_j W[i][j] P[k-major][j] via packed bf16 dot2
    unsigned Pa[4]  = {pq0.x, pq0.z, pq1.x, pq1.z};
    unsigned Pb[4]  = {pq0.y, pq0.w, pq1.y, pq1.w};
    unsigned W0a[4] = {wa0.x, wa0.z, wa1.x, wa1.z};
    unsigned W0b[4] = {wa0.y, wa0.w, wa1.y, wa1.w};
    unsigned W1a[4] = {wb0.x, wb0.z, wb1.x, wb1.z};
    unsigned W1b[4] = {wb0.y, wb0.w, wb1.y, wb1.w};
    float v0[16], v1[16];
#pragma unroll
    for (int i = 0; i < 4; ++i)
#pragma unroll
        for (int k = 0; k < 4; ++k) {
            v0[i * 4 + k] = dot2bf(W0a[i], Pa[k], dot2bf(W0b[i], Pb[k], 0.f));
            v1[i * 4 + k] = dot2bf(W1a[i], Pa[k], dot2bf(W1b[i], Pb[k], 0.f));
        }

    // transpose: m-major stride 17 (odd -> bank-bijective, 2-way = free)
#pragma unroll
    for (int dd = 0; dd < 16; ++dd) {
        red[tid * 17 + dd] = v0[dd];
        red[NM * 17 + tid * 17 + dd] = v1[dd];
    }
    red[tid * 17 + 16] = w0;
    red[NM * 17 + tid * 17 + 16] = w1;
    __syncthreads();                                        // B1

    // column sums: thread (d = tid&15, c = tid>>4) sums m = 16c..16c+15, both halves
    {
        const int d = tid & 15, c = tid >> 4;
        const float* base0 = &red[(c << 4) * 17];
        const float* base1 = base0 + NM * 17;
        float s10 = 0.f, s20 = 0.f, sw0 = 0.f;
        float s11 = 0.f, s21 = 0.f, sw1 = 0.f;
#pragma unroll
        for (int q = 0; q < 16; ++q) {
            float ww0 = base0[q * 17 + 16], vv0 = base0[q * 17 + d];
            float ww1 = base1[q * 17 + 16], vv1 = base1[q * 17 + d];
            float t0 = ww0 * vv0, t1 = ww1 * vv1;
            s10 += t0; s20 += t0 * vv0; sw0 += ww0;
            s11 += t1; s21 += t1 * vv1; sw1 += ww1;
        }
        paru[d * 18 + c] = s10;       parv[d * 18 + c] = s20;
        paru[NM + d * 18 + c] = s11;  parv[NM + d * 18 + c] = s21;
        if (d == 0) { paruW[c] = sw0; paruW[18 + c] = sw1; }
    }
    __syncthreads();                                        // B2

    float sW_f = 0.f;   // live into the output stage (tid<32)
    if (tid < 32) {
        const int h = tid >> 4, dd = tid & 15;
        float sW = 0.f, S1 = 0.f, S2 = 0.f;
#pragma unroll
        for (int c = 0; c < 18; ++c) {
            sW += paruW[h * 18 + c];
            S1 += paru[h * NM + dd * 18 + c];
            S2 += parv[h * NM + dd * 18 + c];
        }
        float mu = S1 / sW;
        float q2 = S2 / sW;
        float ss = fmaxf(q2 - mu * mu, 1e-30f);   // E[v^2]-mu^2 (r4-r13 verified)
        mul[h][dd]  = mu;
        ssl[h][dd]  = ss;
        nhil[h][dd] = -0.5f / ss;
        ltl[h][dd]  = fmaf(-0.5f, __logf(ss), -HALF_LOG_2PI);
        sW_f = sW;
    }
    __syncthreads();                                        // B3

    if (iter < 3) {
        // A[m] = act * sum_d exp(log_p_d)  — linear, like the reference
        float s0 = 0.f, s1 = 0.f;
#pragma unroll
        for (int dd = 0; dd < 16; ++dd) {
            float df0 = v0[dd] - mul[0][dd];
            float df1 = v1[dd] - mul[1][dd];
            s0 += __expf(fmaf(df0 * df0, nhil[0][dd], ltl[0][dd]));
            s1 += __expf(fmaf(df1 * df1, nhil[1][dd], ltl[1][dd]));
        }
        wsL[(size_t)bn0 * NM + tid] = act * s0;   // contiguous stores only
        wsL[(size_t)bn1 * NM + tid] = act * s1;
    } else {
        const int f32 = *flagp;
        if (tid < 32) {
            const int h = tid >> 4, dd = tid & 15;
            const int bnh = h ? bn1 : bn0;
            if (f32) ((float*)outv)[(bnh << 4) + dd] = mul[h][dd];
            else ((__hip_bfloat16*)outv)[(bnh << 4) + dd] = __float2bfloat16(mul[h][dd]);
        }
        if ((tid & 15) == 0 && tid < 32) {        // tid 0 -> h0, tid 16 -> h1
            const int h = tid >> 4;
            const int bnh = h ? bn1 : bn0;
            const int nh  = (h ? (z1 * NUV + uv) : (z0 * NUV + uv));
            float sumR = sW_f;                 // true linear sum_R
            float bv = ldin(beta_v, nh, f32);
            float c = 0.f;
#pragma unroll
            for (int dd = 0; dd < 16; ++dd) c += bv + __logf(ssl[h][dd]);
            c *= sumR;
            float lam = ldin(lambda_, 0, f32);
            float ba  = ldin(beta_a, nh, f32);
            float ao  = 1.f / (1.f + __expf(-(lam * (ba - c))));
            int oi = NB * NN * ND + bnh;
            if (f32) ((float*)outv)[oi] = ao;
            else ((__hip_bfloat16*)outv)[oi] = __float2bfloat16(ao);
        }
    }
}

// sum stage 1: block (b,c) covers 32 rows n = 32c..32c+31 of contiguous
// A[b][n][m]; thread m walks the column (coalesced). Pure adds — one pass.
__global__ __launch_bounds__(288) void sum1_kernel(const float* __restrict__ L,
                                                   float* __restrict__ PS)
{
    const int tid = threadIdx.x;
    const int blk = blockIdx.x;           // b*36 + c
    const int b = blk / NUV;
    const int c = blk % NUV;
    const float* base = L + ((size_t)b * NN + c * 32) * NM + tid;
    float s = 0.f;
#pragma unroll
    for (int r = 0; r < 32; ++r) s += base[r * NM];
    PS[blk * NM + tid] = s;
}

// sum stage 2: combine 36 chunk partials per (b,m) row. 2304 rows.
__global__ void sum2_kernel(const float* __restrict__ PS,
                            float* __restrict__ S)
{
    int t = blockIdx.x * 256 + threadIdx.x;   // b*288 + m
    if (t >= NB * NM) return;
    int b = t / NM, m = t % NM;
    const float* ps = PS + (size_t)b * NUV * NM + m;
    float s = 0.f;
#pragma unroll
    for (int cc = 0; cc < NUV; ++cc) s += ps[cc * NM];
    S[t] = s;
}

extern "C" void kernel_launch(void* const* d_in, const int* in_sizes, int n_in,
                              void* d_out, int out_size, void* d_ws, size_t ws_size,
                              hipStream_t stream)
{
    const void* poses = d_in[0];
    const void* acts  = d_in[1];
    const void* lam   = d_in[2];
    const void* Wb    = d_in[3];
    const void* bv    = d_in[4];
    const void* ba    = d_in[5];

    float* ws  = (float*)d_ws;
    __hip_bfloat16* P  = (__hip_bfloat16*)(ws + OFF_P);
    __hip_bfloat16* Wt = (__hip_bfloat16*)(ws + OFF_WT);
    float* A36 = ws + OFF_ACT;
    float* L   = ws + OFF_L;
    float* S   = ws + OFF_S;
    float* PS  = ws + OFF_PS;
    int*  flag = (int*)(ws + OFF_FLAG);

    prep_kernel<<<292, 256, 0, stream>>>(poses, acts, Wb, P, Wt, A36, flag);

    for (int it = 0; it < 4; ++it) {
        em_iter<<<NB * NN / 2, 288, 0, stream>>>((const unsigned short*)P,
                                                 (const unsigned short*)Wt,
                                                 A36, L, S, bv, ba, lam,
                                                 d_out, flag, it);
        if (it < 3) {
            sum1_kernel<<<NB * NUV, 288, 0, stream>>>(L, PS);
            sum2_kernel<<<9, 256, 0, stream>>>(PS, S);
        }
    }
}

// Round 9
// 209.367 us; speedup vs baseline: 1.1779x; 1.1779x over previous
//
#include <hip/hip_runtime.h>
#include <hip/hip_bf16.h>

// Problem constants
#define NB   8      // batch
#define NM   288    // Bkk = 32*3*3
#define NN   1152   // Cww = 32*6*6
#define NUV  36     // w*w
#define ND   16

// ws layout (float offsets; P/Wt regions hold bf16 in half the space)
#define OFF_P    0
#define SZ_P     (NB*NUV*NM*ND)      // patches, bf16 [b][uv][m][k*4+j]
#define OFF_WT   (OFF_P + SZ_P)
#define SZ_WT    (32*NM*ND)          // W transposed, bf16 [z][m][i*4+j]
#define OFF_ACT  (OFF_WT + SZ_WT)
#define SZ_ACT   (NB*NUV*NM)         // act LINEAR, f32 [b][uv][m]
#define OFF_L    (OFF_ACT + SZ_ACT)
#define SZ_L     (NB*NN*NM)          // A = ap (linear), f32 [b][n][m]
#define OFF_S    (OFF_L + SZ_L)
#define SZ_S     (NB*NM)             // S[b][m] = sum_n A
#define OFF_PS   (OFF_S + SZ_S)
#define SZ_PS    (NB*NUV*NM)         // sum stage-1 partials, [b][c][m]
#define OFF_FLAG (OFF_PS + SZ_PS)    // dtype flag

#define HALF_LOG_2PI 0.9189385332046727f
#define INV_NN       (1.0f/1152.0f)

__device__ __forceinline__ float ldin(const void* p, int i, int f32) {
    return f32 ? ((const float*)p)[i]
               : __bfloat162float(((const __hip_bfloat16*)p)[i]);
}

__device__ __forceinline__ unsigned short bfbits(float f) {
    __hip_bfloat16 h = __float2bfloat16(f);
    return __builtin_bit_cast(unsigned short, h);
}

// packed bf16x2 dot with f32 accumulate: d = a.lo*b.lo + a.hi*b.hi + c
__device__ __forceinline__ float dot2bf(unsigned a, unsigned b, float c) {
    float d;
    asm("v_dot2_f32_bf16 %0, %1, %2, %3" : "=v"(d) : "v"(a), "v"(b), "v"(c));
    return d;
}

// inline dtype sniff (r3-r13 verified: flag==0 on this harness)
__device__ __forceinline__ int sniff(const unsigned short* u16) {
    int wild = 0;
    for (int i = 0; i < 64; ++i) {
        int ex = (u16[i] >> 7) & 0xFF;
        if (ex >= 133) ++wild;
    }
    return (wild >= 4) ? 1 : 0;
}

// (b,s)-tiled prep: stage poses[b,:,s,:,:] + acts[b,s,:,:] in LDS, emit bf16 P
// (uint4 stores) and f32 act (LINEAR). Blocks 256..291 transpose W.
__global__ __launch_bounds__(256) void prep_kernel(
    const void* __restrict__ poses, const void* __restrict__ acts,
    const void* __restrict__ Wb, __hip_bfloat16* __restrict__ P,
    __hip_bfloat16* __restrict__ Wt, float* __restrict__ A36,
    int* __restrict__ flagw)
{
    const int blk = blockIdx.x;
    const int tid = threadIdx.x;
    __shared__ int lflag;
    if (tid == 0) {
        int f = sniff((const unsigned short*)poses);
        lflag = f;
        if (blk == 0) *flagw = f;
    }
    __syncthreads();
    const int f32 = lflag;

    if (blk < 256) {
        __shared__ float ps[16 * 196];
        __shared__ float asld[196];
        const int b = blk >> 5, s = blk & 31;
        for (int e = tid; e < 16 * 196; e += 256) {
            int c = e / 196, hw = e % 196;
            ps[e] = ldin(poses, ((b * 16 + c) * 32 + s) * 196 + hw, f32);
        }
        for (int e = tid; e < 196; e += 256)
            asld[e] = ldin(acts, (b * 32 + s) * 196 + e, f32);
        __syncthreads();
        // P emit: 324 rows x 2 halves; one uint4 (8 bf16) per work item
        for (int o2 = tid; o2 < 648; o2 += 256) {
            int row = o2 >> 1, half = o2 & 1;
            int uv = row / 9, xy = row % 9;
            int u = uv / 6, vv2 = uv % 6;
            int x = xy / 3, y = xy % 3;
            unsigned pk[4];
#pragma unroll
            for (int h = 0; h < 4; ++h) {
                unsigned lohi[2];
#pragma unroll
                for (int e = 0; e < 2; ++e) {
                    int kj = half * 8 + h * 2 + e;
                    int k = kj >> 2, j = kj & 3;
                    int idx = u * 96 + vv2 * 16 + j * 4 + k;   // torch view scramble
                    int c = idx / 36, rem = idx % 36;
                    int wi = rem / 6, wj = rem % 6;
                    lohi[e] = bfbits(ps[c * 196 + (2 * wi + x) * 14 + (2 * wj + y)]);
                }
                pk[h] = lohi[0] | (lohi[1] << 16);
            }
            *((uint4*)(P + (((size_t)((b * 36 + uv) * 288 + s * 9 + xy)) << 4) + half * 8)) =
                make_uint4(pk[0], pk[1], pk[2], pk[3]);
        }
        for (int o = tid; o < 324; o += 256) {
            int uv = o / 9, xy = o % 9;
            int u = uv / 6, vv2 = uv % 6;
            int x = xy / 3, y = xy % 3;
            A36[(b * 36 + uv) * 288 + s * 9 + xy] =
                asld[(2 * u + x) * 14 + (2 * vv2 + y)];    // linear act
        }
    } else {
        int idx = (blk - 256) * 256 + tid;    // 0..9215 (z,m) pairs
        int z = idx / 288, m = idx % 288;
        unsigned pk[8];
#pragma unroll
        for (int h = 0; h < 8; ++h) {
            unsigned lo = bfbits(ldin(Wb, m * 512 + z * 16 + 2 * h, f32));
            unsigned hi = bfbits(ldin(Wb, m * 512 + z * 16 + 2 * h + 1, f32));
            pk[h] = lo | (hi << 16);
        }
        uint4* dst = (uint4*)(Wt + idx * 16);
        dst[0] = make_uint4(pk[0], pk[1], pk[2], pk[3]);
        dst[1] = make_uint4(pk[4], pk[5], pk[6], pk[7]);
    }
}

// One block per (b,n), 256 THREADS (4 full waves — r5's 288 = 4.5 waves took
// 5 wave contexts, capping residency at 6 blocks/CU; 4-wave blocks + 21.9 KB
// LDS allow 7-8 resident -> ~28 waves). m 256..287 ride as second items on
// the LAST wave (tid>=224, m2=tid+32) so the extra dot2/epilogue work and the
// finalize (wave 0, tid<16) land on different waves. v re-read from red[] in
// the epilogue (red untouched between B1 and epilogue) keeps VGPR low.
// r6/r8 lessons: many small loosely-coupled blocks win; no fusion, no ILP-2.
// Linear EM throughout (w = R*act; A = act*sum exp; no log/LSE).
// XCD swizzle: blockIdx = (g>>3)*256 + z*8 + (g&7), g = b*36+uv.
__global__ __launch_bounds__(256, 7) void em_iter(
    const unsigned short* __restrict__ wsP, const unsigned short* __restrict__ wsWt,
    const float* __restrict__ wsA, float* __restrict__ wsL,
    const float* __restrict__ wsS,
    const void* __restrict__ beta_v,
    const void* __restrict__ beta_a,
    const void* __restrict__ lambda_,
    void* __restrict__ outv, const int* __restrict__ flagp, int iter)
{
    __shared__ float red[NM * 17];   // [m][col]: 0..15 = v[d], 16 = w (19.6 KB)
    __shared__ float paru[16 * 16];  // [d][c] partial sum(w*v), c in [0,16)
    __shared__ float parv[16 * 16];  // [d][c] partial sum(w*v*v)
    __shared__ float paruW[16];      // [c] partial sum(w)
    __shared__ float mul[16], nhil[16], ltl[16], ssl[16];

    const int tid = threadIdx.x;          // m1 = tid
    const int B   = blockIdx.x;
    const int rr  = B & 255;
    const int z   = rr >> 3;
    const int g   = ((B >> 8) << 3) | (rr & 7);   // b*36+uv
    const int b   = g / NUV;
    const int uv  = g % NUV;
    const int n   = z * NUV + uv;
    const int bn  = b * NN + n;

    const bool dual = (tid >= 224);       // last wave carries m2 = tid+32
    const int  m2   = tid + 32;           // in [256,288) when dual

    // all global loads issued up front (bf16 W/P rows stay packed)
    const uint4* Wq = (const uint4*)(wsWt + ((z * NM + tid) << 4));
    const uint4* Pq = (const uint4*)(wsP + ((g * NM + tid) << 4));
    uint4 wq0 = Wq[0], wq1 = Wq[1];
    uint4 pq0 = Pq[0], pq1 = Pq[1];
    const float act1 = wsA[g * NM + tid];
    float w1;
    if (iter == 0) w1 = act1 * INV_NN;
    else w1 = wsL[(size_t)bn * NM + tid] * act1 / wsS[b * NM + tid];

    uint4 wq0b, wq1b, pq0b, pq1b;
    float act2 = 0.f, w2 = 0.f;
    if (dual) {
        const uint4* Wq2 = (const uint4*)(wsWt + ((z * NM + m2) << 4));
        const uint4* Pq2 = (const uint4*)(wsP + ((g * NM + m2) << 4));
        wq0b = Wq2[0]; wq1b = Wq2[1];
        pq0b = Pq2[0]; pq1b = Pq2[1];
        act2 = wsA[g * NM + m2];
        if (iter == 0) w2 = act2 * INV_NN;
        else w2 = wsL[(size_t)bn * NM + m2] * act2 / wsS[b * NM + m2];
    }

    // votes v[i*4+k] = sum_j W[i][j] P[k-major][j] via packed bf16 dot2;
    // store straight to LDS (stride 17: odd -> bank-bijective, 2-way free)
    {
        unsigned Wa[4]  = {wq0.x, wq0.z, wq1.x, wq1.z};
        unsigned Wb_[4] = {wq0.y, wq0.w, wq1.y, wq1.w};
        unsigned Pa[4]  = {pq0.x, pq0.z, pq1.x, pq1.z};
        unsigned Pb[4]  = {pq0.y, pq0.w, pq1.y, pq1.w};
#pragma unroll
        for (int i = 0; i < 4; ++i)
#pragma unroll
            for (int k = 0; k < 4; ++k)
                red[tid * 17 + i * 4 + k] =
                    dot2bf(Wa[i], Pa[k], dot2bf(Wb_[i], Pb[k], 0.f));
        red[tid * 17 + 16] = w1;
    }
    if (dual) {
        unsigned Wa[4]  = {wq0b.x, wq0b.z, wq1b.x, wq1b.z};
        unsigned Wb_[4] = {wq0b.y, wq0b.w, wq1b.y, wq1b.w};
        unsigned Pa[4]  = {pq0b.x, pq0b.z, pq1b.x, pq1b.z};
        unsigned Pb[4]  = {pq0b.y, pq0b.w, pq1b.y, pq1b.w};
#pragma unroll
        for (int i = 0; i < 4; ++i)
#pragma unroll
            for (int k = 0; k < 4; ++k)
                red[m2 * 17 + i * 4 + k] =
                    dot2bf(Wa[i], Pa[k], dot2bf(Wb_[i], Pb[k], 0.f));
        red[m2 * 17 + 16] = w2;
    }
    __syncthreads();                                        // B1

    // column sums: thread (d = tid&15, c = tid>>4) sums m = 18c..18c+17
    {
        const int d = tid & 15, c = tid >> 4;   // c in [0,16)
        const float* base = &red[(c * 18) * 17];
        float s1 = 0.f, s2 = 0.f, sw = 0.f;
#pragma unroll
        for (int q = 0; q < 18; ++q) {
            float ww = base[q * 17 + 16];
            float vv = base[q * 17 + d];
            float t1 = ww * vv;
            s1 += t1; s2 += t1 * vv; sw += ww;
        }
        paru[d * 16 + c] = s1;
        parv[d * 16 + c] = s2;
        if (d == 0) paruW[c] = sw;
    }
    __syncthreads();                                        // B2

    float sW_f = 0.f;   // live into the output stage (tid<16)
    if (tid < 16) {
        float sW = 0.f, S1 = 0.f, S2 = 0.f;
#pragma unroll
        for (int c = 0; c < 16; ++c) {
            sW += paruW[c];
            S1 += paru[tid * 16 + c];
            S2 += parv[tid * 16 + c];
        }
        float mu = S1 / sW;
        float q2 = S2 / sW;
        float ss = fmaxf(q2 - mu * mu, 1e-30f);   // E[v^2]-mu^2 (r4-r13 verified)
        mul[tid]  = mu;
        ssl[tid]  = ss;
        nhil[tid] = -0.5f / ss;
        ltl[tid]  = fmaf(-0.5f, __logf(ss), -HALF_LOG_2PI);
        sW_f = sW;
    }
    __syncthreads();                                        // B3

    if (iter < 3) {
        // A[m] = act * sum_d exp(log_p_d) — v re-read from red (still intact)
        float s = 0.f;
#pragma unroll
        for (int dd = 0; dd < 16; ++dd) {
            float df = red[tid * 17 + dd] - mul[dd];
            s += __expf(fmaf(df * df, nhil[dd], ltl[dd]));
        }
        wsL[(size_t)bn * NM + tid] = act1 * s;
        if (dual) {
            float s2 = 0.f;
#pragma unroll
            for (int dd = 0; dd < 16; ++dd) {
                float df = red[m2 * 17 + dd] - mul[dd];
                s2 += __expf(fmaf(df * df, nhil[dd], ltl[dd]));
            }
            wsL[(size_t)bn * NM + m2] = act2 * s2;
        }
    } else {
        const int f32 = *flagp;
        if (tid < 16) {
            if (f32) ((float*)outv)[(bn << 4) + tid] = mul[tid];
            else ((__hip_bfloat16*)outv)[(bn << 4) + tid] = __float2bfloat16(mul[tid]);
        }
        if (tid == 0) {
            float sumR = sW_f;                 // true linear sum_R
            float bv = ldin(beta_v, n, f32);
            float c = 0.f;
#pragma unroll
            for (int dd = 0; dd < 16; ++dd) c += bv + __logf(ssl[dd]);
            c *= sumR;
            float lam = ldin(lambda_, 0, f32);
            float ba  = ldin(beta_a, n, f32);
            float ao  = 1.f / (1.f + __expf(-(lam * (ba - c))));
            int oi = NB * NN * ND + bn;
            if (f32) ((float*)outv)[oi] = ao;
            else ((__hip_bfloat16*)outv)[oi] = __float2bfloat16(ao);
        }
    }
}

// sum stage 1: block (b,c) covers 32 rows n = 32c..32c+31 of contiguous
// A[b][n][m]; thread m walks the column (coalesced). Pure adds — one pass.
__global__ __launch_bounds__(288) void sum1_kernel(const float* __restrict__ L,
                                                   float* __restrict__ PS)
{
    const int tid = threadIdx.x;
    const int blk = blockIdx.x;           // b*36 + c
    const int b = blk / NUV;
    const int c = blk % NUV;
    const float* base = L + ((size_t)b * NN + c * 32) * NM + tid;
    float s = 0.f;
#pragma unroll
    for (int r = 0; r < 32; ++r) s += base[r * NM];
    PS[blk * NM + tid] = s;
}

// sum stage 2: combine 36 chunk partials per (b,m) row. 2304 rows.
__global__ void sum2_kernel(const float* __restrict__ PS,
                            float* __restrict__ S)
{
    int t = blockIdx.x * 256 + threadIdx.x;   // b*288 + m
    if (t >= NB * NM) return;
    int b = t / NM, m = t % NM;
    const float* ps = PS + (size_t)b * NUV * NM + m;
    float s = 0.f;
#pragma unroll
    for (int cc = 0; cc < NUV; ++cc) s += ps[cc * NM];
    S[t] = s;
}

extern "C" void kernel_launch(void* const* d_in, const int* in_sizes, int n_in,
                              void* d_out, int out_size, void* d_ws, size_t ws_size,
                              hipStream_t stream)
{
    const void* poses = d_in[0];
    const void* acts  = d_in[1];
    const void* lam   = d_in[2];
    const void* Wb    = d_in[3];
    const void* bv    = d_in[4];
    const void* ba    = d_in[5];

    float* ws  = (float*)d_ws;
    __hip_bfloat16* P  = (__hip_bfloat16*)(ws + OFF_P);
    __hip_bfloat16* Wt = (__hip_bfloat16*)(ws + OFF_WT);
    float* A36 = ws + OFF_ACT;
    float* L   = ws + OFF_L;
    float* S   = ws + OFF_S;
    float* PS  = ws + OFF_PS;
    int*  flag = (int*)(ws + OFF_FLAG);

    prep_kernel<<<292, 256, 0, stream>>>(poses, acts, Wb, P, Wt, A36, flag);

    for (int it = 0; it < 4; ++it) {
        em_iter<<<NB * NN, 256, 0, stream>>>((const unsigned short*)P,
                                             (const unsigned short*)Wt,
                                             A36, L, S, bv, ba, lam,
                                             d_out, flag, it);
        if (it < 3) {
            sum1_kernel<<<NB * NUV, 288, 0, stream>>>(L, PS);
            sum2_kernel<<<9, 256, 0, stream>>>(PS, S);
        }
    }
}

// Round 10
// 198.618 us; speedup vs baseline: 1.2417x; 1.0541x over previous
//
#include <hip/hip_runtime.h>
#include <hip/hip_bf16.h>

// Problem constants
#define NB   8      // batch
#define NM   288    // Bkk = 32*3*3
#define NN   1152   // Cww = 32*6*6
#define NUV  36     // w*w
#define ND   16

// ws layout (float offsets; P/Wt regions hold bf16 in half the space)
#define OFF_P    0
#define SZ_P     (NB*NUV*NM*ND)      // patches, bf16 [b][uv][m][k*4+j]
#define OFF_WT   (OFF_P + SZ_P)
#define SZ_WT    (32*NM*ND)          // W transposed, bf16 [z][m][i*4+j]
#define OFF_ACT  (OFF_WT + SZ_WT)
#define SZ_ACT   (NB*NUV*NM)         // act LINEAR, f32 [b][uv][m]
#define OFF_L    (OFF_ACT + SZ_ACT)
#define SZ_L     (NB*NN*NM)          // A = ap (linear), f32 [b][n][m]
#define OFF_S    (OFF_L + SZ_L)
#define SZ_S     (NB*NM)             // S[b][m] = sum_n A
#define OFF_PS   (OFF_S + SZ_S)
#define SZ_PS    (NB*NUV*NM)         // sum stage-1 partials, [b][c][m]
#define OFF_FLAG (OFF_PS + SZ_PS)    // dtype flag

#define HALF_LOG_2PI 0.9189385332046727f
#define INV_NN       (1.0f/1152.0f)

__device__ __forceinline__ float ldin(const void* p, int i, int f32) {
    return f32 ? ((const float*)p)[i]
               : __bfloat162float(((const __hip_bfloat16*)p)[i]);
}

__device__ __forceinline__ float b2f(unsigned short u) {
    __hip_bfloat16 h = __builtin_bit_cast(__hip_bfloat16, u);
    return __bfloat162float(h);
}

__device__ __forceinline__ unsigned short bfbits(float f) {
    __hip_bfloat16 h = __float2bfloat16(f);
    return __builtin_bit_cast(unsigned short, h);
}

// packed bf16x2 dot with f32 accumulate: d = a.lo*b.lo + a.hi*b.hi + c
__device__ __forceinline__ float dot2bf(unsigned a, unsigned b, float c) {
    float d;
    asm("v_dot2_f32_bf16 %0, %1, %2, %3" : "=v"(d) : "v"(a), "v"(b), "v"(c));
    return d;
}

// inline dtype sniff (r3-r13 verified: flag==0 == bf16 on this harness)
__device__ __forceinline__ int sniff(const unsigned short* u16) {
    int wild = 0;
    for (int i = 0; i < 64; ++i) {
        int ex = (u16[i] >> 7) & 0xFF;
        if (ex >= 133) ++wild;
    }
    return (wild >= 4) ? 1 : 0;
}

// (b,s)-tiled prep: stage poses[b,:,s,:,:] + acts[b,s,:,:] in LDS, emit bf16 P
// (uint4 stores) and f32 act (LINEAR). Blocks 256..291 transpose W.
// r10: bf16 FAST PATH vectorized (G13 — hipcc never vectorizes scalar bf16):
// pose staging 784 uint2 loads (4 bf16, 8B-aligned: 196=49*4) vs 3136 scalar;
// W-transpose reads 2xuint4 (the word layout already matches pk packing).
__global__ __launch_bounds__(256) void prep_kernel(
    const void* __restrict__ poses, const void* __restrict__ acts,
    const void* __restrict__ Wb, __hip_bfloat16* __restrict__ P,
    __hip_bfloat16* __restrict__ Wt, float* __restrict__ A36,
    int* __restrict__ flagw)
{
    const int blk = blockIdx.x;
    const int tid = threadIdx.x;
    __shared__ int lflag;
    if (tid == 0) {
        int f = sniff((const unsigned short*)poses);
        lflag = f;
        if (blk == 0) *flagw = f;
    }
    __syncthreads();
    const int f32 = lflag;

    if (blk < 256) {
        __shared__ float ps[16 * 196];
        __shared__ float asld[196];
        const int b = blk >> 5, s = blk & 31;
        if (!f32) {
            const unsigned short* pu = (const unsigned short*)poses;
            for (int e = tid; e < 784; e += 256) {
                int c = e / 49, off = (e % 49) * 4;
                size_t base = ((size_t)(b * 16 + c) * 32 + s) * 196 + off;
                uint2 q = *(const uint2*)(pu + base);   // 4 bf16, 8B aligned
                ps[c * 196 + off + 0] = b2f((unsigned short)(q.x & 0xffff));
                ps[c * 196 + off + 1] = b2f((unsigned short)(q.x >> 16));
                ps[c * 196 + off + 2] = b2f((unsigned short)(q.y & 0xffff));
                ps[c * 196 + off + 3] = b2f((unsigned short)(q.y >> 16));
            }
            const unsigned short* au = (const unsigned short*)acts;
            for (int e = tid; e < 49; e += 256) {
                int off = e * 4;
                uint2 q = *(const uint2*)(au + ((size_t)(b * 32 + s) * 196 + off));
                asld[off + 0] = b2f((unsigned short)(q.x & 0xffff));
                asld[off + 1] = b2f((unsigned short)(q.x >> 16));
                asld[off + 2] = b2f((unsigned short)(q.y & 0xffff));
                asld[off + 3] = b2f((unsigned short)(q.y >> 16));
            }
        } else {
            for (int e = tid; e < 16 * 196; e += 256) {
                int c = e / 196, hw = e % 196;
                ps[e] = ((const float*)poses)[((b * 16 + c) * 32 + s) * 196 + hw];
            }
            for (int e = tid; e < 196; e += 256)
                asld[e] = ((const float*)acts)[(b * 32 + s) * 196 + e];
        }
        __syncthreads();
        // P emit: 324 rows x 2 halves; one uint4 (8 bf16) per work item
        for (int o2 = tid; o2 < 648; o2 += 256) {
            int row = o2 >> 1, half = o2 & 1;
            int uv = row / 9, xy = row % 9;
            int u = uv / 6, vv2 = uv % 6;
            int x = xy / 3, y = xy % 3;
            unsigned pk[4];
#pragma unroll
            for (int h = 0; h < 4; ++h) {
                unsigned lohi[2];
#pragma unroll
                for (int e = 0; e < 2; ++e) {
                    int kj = half * 8 + h * 2 + e;
                    int k = kj >> 2, j = kj & 3;
                    int idx = u * 96 + vv2 * 16 + j * 4 + k;   // torch view scramble
                    int c = idx / 36, rem = idx % 36;
                    int wi = rem / 6, wj = rem % 6;
                    lohi[e] = bfbits(ps[c * 196 + (2 * wi + x) * 14 + (2 * wj + y)]);
                }
                pk[h] = lohi[0] | (lohi[1] << 16);
            }
            *((uint4*)(P + (((size_t)((b * 36 + uv) * 288 + s * 9 + xy)) << 4) + half * 8)) =
                make_uint4(pk[0], pk[1], pk[2], pk[3]);
        }
        for (int o = tid; o < 324; o += 256) {
            int uv = o / 9, xy = o % 9;
            int u = uv / 6, vv2 = uv % 6;
            int x = xy / 3, y = xy % 3;
            A36[(b * 36 + uv) * 288 + s * 9 + xy] =
                asld[(2 * u + x) * 14 + (2 * vv2 + y)];    // linear act
        }
    } else {
        int idx = (blk - 256) * 256 + tid;    // 0..9215 (z,m) pairs
        int z = idx / 288, m = idx % 288;
        uint4* dst = (uint4*)(Wt + idx * 16);
        if (!f32) {
            // 16 consecutive bf16 = 32B; word packing already (lo|hi<<16)
            const uint4* src = (const uint4*)((const unsigned short*)Wb + m * 512 + z * 16);
            dst[0] = src[0];
            dst[1] = src[1];
        } else {
            unsigned pk[8];
#pragma unroll
            for (int h = 0; h < 8; ++h) {
                unsigned lo = bfbits(((const float*)Wb)[m * 512 + z * 16 + 2 * h]);
                unsigned hi = bfbits(((const float*)Wb)[m * 512 + z * 16 + 2 * h + 1]);
                pk[h] = lo | (hi << 16);
            }
            dst[0] = make_uint4(pk[0], pk[1], pk[2], pk[3]);
            dst[1] = make_uint4(pk[4], pk[5], pk[6], pk[7]);
        }
    }
}

// One block per (b,n), 288 threads — r5 structure VERBATIM (201.6 µs verified;
// granularity ledger: r6 9-wave +34, r8 2-n ILP +45, r9 256+dual-wave +7.8 —
// every restructure lost to this shape: many small loosely-coupled blocks).
// Linear EM throughout (w = R*act; A = act*sum exp; no log/LSE).
// XCD swizzle: blockIdx = (g>>3)*256 + z*8 + (g&7), g = b*36+uv.
__global__ __launch_bounds__(288, 4) void em_iter(
    const unsigned short* __restrict__ wsP, const unsigned short* __restrict__ wsWt,
    const float* __restrict__ wsA, float* __restrict__ wsL,
    const float* __restrict__ wsS,
    const void* __restrict__ beta_v,
    const void* __restrict__ beta_a,
    const void* __restrict__ lambda_,
    void* __restrict__ outv, const int* __restrict__ flagp, int iter)
{
    __shared__ float red[NM * 17];   // [m][col]: 0..15 = v[d], 16 = w  (19.6 KB)
    __shared__ float paru[NM];       // [d][c] partial sum(w*v)
    __shared__ float parv[NM];       // [d][c] partial sum(w*v*v)
    __shared__ float paruW[18];      // [c] partial sum(w)
    __shared__ float mul[16], nhil[16], ltl[16], ssl[16];

    const int tid = threadIdx.x;          // == m
    const int B   = blockIdx.x;
    const int rr  = B & 255;
    const int z   = rr >> 3;
    const int g   = ((B >> 8) << 3) | (rr & 7);   // b*36+uv
    const int b   = g / NUV;
    const int uv  = g % NUV;
    const int n   = z * NUV + uv;
    const int bn  = b * NN + n;

    // all global loads issued up front (bf16 W/P rows stay packed)
    const uint4* Wq = (const uint4*)(wsWt + ((z * NM + tid) << 4));
    const uint4* Pq = (const uint4*)(wsP + ((g * NM + tid) << 4));
    uint4 wq0 = Wq[0], wq1 = Wq[1];
    uint4 pq0 = Pq[0], pq1 = Pq[1];
    const float act = wsA[g * NM + tid];   // linear act
    float w;
    if (iter == 0) {
        w = act * INV_NN;
    } else {
        float Ap = wsL[(size_t)bn * NM + tid];
        float Sv = wsS[b * NM + tid];
        w = Ap * act / Sv;                 // R*act, linear (matches reference)
    }

    // votes v[i*4+k] = sum_j W[i][j] P[k-major][j] via packed bf16 dot2
    unsigned Wa[4]  = {wq0.x, wq0.z, wq1.x, wq1.z};   // (j0,j1) of i
    unsigned Wb_[4] = {wq0.y, wq0.w, wq1.y, wq1.w};   // (j2,j3) of i
    unsigned Pa[4]  = {pq0.x, pq0.z, pq1.x, pq1.z};   // (j0,j1) of k
    unsigned Pb[4]  = {pq0.y, pq0.w, pq1.y, pq1.w};   // (j2,j3) of k
    float v[16];
#pragma unroll
    for (int i = 0; i < 4; ++i)
#pragma unroll
        for (int k = 0; k < 4; ++k)
            v[i * 4 + k] = dot2bf(Wa[i], Pa[k], dot2bf(Wb_[i], Pb[k], 0.f));

    // transpose: m-major stride 17 (odd -> bank-bijective, 2-way = free)
#pragma unroll
    for (int dd = 0; dd < 16; ++dd) red[tid * 17 + dd] = v[dd];
    red[tid * 17 + 16] = w;
    __syncthreads();                                        // B1

    // column sums: thread (d = tid&15, c = tid>>4) sums m = 16c..16c+15
    {
        const int d = tid & 15, c = tid >> 4;
        const float* base = &red[(c << 4) * 17];
        float s1 = 0.f, s2 = 0.f, sw = 0.f;
#pragma unroll
        for (int q = 0; q < 16; ++q) {
            float ww = base[q * 17 + 16];
            float vv = base[q * 17 + d];
            float t1 = ww * vv;
            s1 += t1; s2 += t1 * vv; sw += ww;
        }
        paru[d * 18 + c] = s1;
        parv[d * 18 + c] = s2;
        if (d == 0) paruW[c] = sw;
    }
    __syncthreads();                                        // B2

    float sW_f = 0.f;   // live into the output stage (tid<16)
    if (tid < 16) {
        float sW = 0.f, S1 = 0.f, S2 = 0.f;
#pragma unroll
        for (int c = 0; c < 18; ++c) {
            sW += paruW[c];
            S1 += paru[tid * 18 + c];
            S2 += parv[tid * 18 + c];
        }
        float mu = S1 / sW;
        float q2 = S2 / sW;
        float ss = fmaxf(q2 - mu * mu, 1e-30f);   // E[v^2]-mu^2 (r4-r13 verified)
        mul[tid]  = mu;
        ssl[tid]  = ss;
        nhil[tid] = -0.5f / ss;
        ltl[tid]  = fmaf(-0.5f, __logf(ss), -HALF_LOG_2PI);
        sW_f = sW;
    }
    __syncthreads();                                        // B3

    if (iter < 3) {
        // A[m] = act * sum_d exp(log_p_d)  — linear, like the reference
        float s = 0.f;
#pragma unroll
        for (int dd = 0; dd < 16; ++dd) {
            float df = v[dd] - mul[dd];
            s += __expf(fmaf(df * df, nhil[dd], ltl[dd]));
        }
        wsL[(size_t)bn * NM + tid] = act * s;   // contiguous store only
    } else {
        const int f32 = *flagp;
        if (tid < 16) {
            if (f32) ((float*)outv)[(bn << 4) + tid] = mul[tid];
            else ((__hip_bfloat16*)outv)[(bn << 4) + tid] = __float2bfloat16(mul[tid]);
        }
        if (tid == 0) {
            float sumR = sW_f;                 // true linear sum_R
            float bv = ldin(beta_v, n, f32);
            float c = 0.f;
#pragma unroll
            for (int dd = 0; dd < 16; ++dd) c += bv + __logf(ssl[dd]);
            c *= sumR;
            float lam = ldin(lambda_, 0, f32);
            float ba  = ldin(beta_a, n, f32);
            float ao  = 1.f / (1.f + __expf(-(lam * (ba - c))));
            int oi = NB * NN * ND + bn;
            if (f32) ((float*)outv)[oi] = ao;
            else ((__hip_bfloat16*)outv)[oi] = __float2bfloat16(ao);
        }
    }
}

// sum stage 1: block (b,c) covers 32 rows n = 32c..32c+31 of contiguous
// A[b][n][m]; thread m walks the column (coalesced). Pure adds — one pass.
__global__ __launch_bounds__(288) void sum1_kernel(const float* __restrict__ L,
                                                   float* __restrict__ PS)
{
    const int tid = threadIdx.x;
    const int blk = blockIdx.x;           // b*36 + c
    const int b = blk / NUV;
    const int c = blk % NUV;
    const float* base = L + ((size_t)b * NN + c * 32) * NM + tid;
    float s = 0.f;
#pragma unroll
    for (int r = 0; r < 32; ++r) s += base[r * NM];
    PS[blk * NM + tid] = s;
}

// sum stage 2: combine 36 chunk partials per (b,m) row. 2304 rows.
__global__ void sum2_kernel(const float* __restrict__ PS,
                            float* __restrict__ S)
{
    int t = blockIdx.x * 256 + threadIdx.x;   // b*288 + m
    if (t >= NB * NM) return;
    int b = t / NM, m = t % NM;
    const float* ps = PS + (size_t)b * NUV * NM + m;
    float s = 0.f;
#pragma unroll
    for (int cc = 0; cc < NUV; ++cc) s += ps[cc * NM];
    S[t] = s;
}

extern "C" void kernel_launch(void* const* d_in, const int* in_sizes, int n_in,
                              void* d_out, int out_size, void* d_ws, size_t ws_size,
                              hipStream_t stream)
{
    const void* poses = d_in[0];
    const void* acts  = d_in[1];
    const void* lam   = d_in[2];
    const void* Wb    = d_in[3];
    const void* bv    = d_in[4];
    const void* ba    = d_in[5];

    float* ws  = (float*)d_ws;
    __hip_bfloat16* P  = (__hip_bfloat16*)(ws + OFF_P);
    __hip_bfloat16* Wt = (__hip_bfloat16*)(ws + OFF_WT);
    float* A36 = ws + OFF_ACT;
    float* L   = ws + OFF_L;
    float* S   = ws + OFF_S;
    float* PS  = ws + OFF_PS;
    int*  flag = (int*)(ws + OFF_FLAG);

    prep_kernel<<<292, 256, 0, stream>>>(poses, acts, Wb, P, Wt, A36, flag);

    for (int it = 0; it < 4; ++it) {
        em_iter<<<NB * NN, 288, 0, stream>>>((const unsigned short*)P,
                                             (const unsigned short*)Wt,
                                             A36, L, S, bv, ba, lam,
                                             d_out, flag, it);
        if (it < 3) {
            sum1_kernel<<<NB * NUV, 288, 0, stream>>>(L, PS);
            sum2_kernel<<<9, 256, 0, stream>>>(PS, S);
        }
    }
}